// Round 3
// baseline (318.919 us; speedup 1.0000x reference)
//
#include <hip/hip_runtime.h>
#include <hip/hip_cooperative_groups.h>

namespace cg = cooperative_groups;

#define N_NODES 50000
#define N_EDGES 800000
#define IN_F    256
#define HIDDEN  128

#define BUCKET_SZ 64                      // rows per bucket
#define NB        782                     // ceil(N_NODES / 64)
#define NBINS     1024                    // padded scan width (4 per thread x 256)
#define EBLOCK    3328                    // edges per partition task (13 x 256)
#define EPT       13                      // edges per thread
#define EBLOCKS   241                     // ceil(800000 / 3328)
#define LBLOCKS   782                     // linear tasks (64 rows each)
#define NTASKS    1023                    // EBLOCKS + LBLOCKS
#define CAP       1300                    // bucket capacity (mean 1024, +8.6 sigma)
#define OV_CAP    4096                    // overflow list capacity
#define MEGA_MAXG 1024                    // 4 blocks/CU x 256 CUs

// LDS union: partition needs the most (39040 B); linear 32768; gather 11184.
#define SMEM_BYTES 39040

typedef __attribute__((ext_vector_type(8))) short bf16x8;
typedef __attribute__((ext_vector_type(4))) float f32x4;

__device__ inline unsigned short f2bf(float f) {
    unsigned u = __float_as_uint(f);
    u += 0x7FFF + ((u >> 16) & 1);          // round-to-nearest-even
    return (unsigned short)(u >> 16);
}
__device__ inline bf16x8 cvt8(float4 a, float4 b) {
    bf16x8 r;
    r[0] = (short)f2bf(a.x); r[1] = (short)f2bf(a.y);
    r[2] = (short)f2bf(a.z); r[3] = (short)f2bf(a.w);
    r[4] = (short)f2bf(b.x); r[5] = (short)f2bf(b.y);
    r[6] = (short)f2bf(b.z); r[7] = (short)f2bf(b.w);
    return r;
}
__device__ inline float bfLo(unsigned u) { return __uint_as_float(u << 16); }
__device__ inline float bfHi(unsigned u) { return __uint_as_float(u & 0xFFFF0000u); }

// ---------------------------------------------------------------------------
// Edge partition task: 3328 edges -> bucket-sorted runs in part[].
// Key: [31:22] bucket (r>>6), [21:16] row-in-bucket, [15:0] col.
// ---------------------------------------------------------------------------
__device__ __forceinline__ void do_partition(
    char* smem, int task,
    const int* __restrict__ adj_row, const int* __restrict__ adj_col,
    const float* __restrict__ adj_val, int* __restrict__ cursor,
    int2* __restrict__ part, int4* __restrict__ ovbuf, int* __restrict__ ovcnt)
{
    int2* lbuf  = (int2*)smem;                    // 26624 B
    int*  lofs  = (int*)(smem + 26624);           // 4096 B (counts -> excl offsets)
    int*  lcur  = (int*)(smem + 30720);           // 4096 B
    int*  gbase = (int*)(smem + 34816);           // 3200 B (782 used)
    int*  tsum  = (int*)(smem + 38016);           // 1024 B

    const int tid  = threadIdx.x;
    const int base = task * EBLOCK;
    const int n    = min(EBLOCK, N_EDGES - base);

    for (int i = tid; i < NBINS; i += 256) lofs[i] = 0;
    __syncthreads();

    unsigned pk[EPT]; float pv[EPT];
#pragma unroll
    for (int i = 0; i < EPT; ++i) {
        int li = tid + i * 256;
        bool ok = li < n;
        int ee = ok ? (base + li) : base;
        int r = adj_row[ee], c = adj_col[ee];
        float v = adj_val[ee];
        if (ok) {
            unsigned bk = (unsigned)r >> 6;
            pk[i] = (bk << 22) | (((unsigned)r & 63u) << 16) | (unsigned)c;
            pv[i] = v;
            atomicAdd(&lofs[bk], 1);
        } else pk[i] = 0xFFFFFFFFu;
    }
    __syncthreads();

    // exclusive scan over 1024 bins: 4 per thread + Hillis-Steele over 256
    int s0 = lofs[tid * 4], s1 = lofs[tid * 4 + 1];
    int s2 = lofs[tid * 4 + 2], s3 = lofs[tid * 4 + 3];
    int mysum = s0 + s1 + s2 + s3;
    tsum[tid] = mysum;
    __syncthreads();
#pragma unroll
    for (int off = 1; off < 256; off <<= 1) {
        int t = (tid >= off) ? tsum[tid - off] : 0;
        __syncthreads();
        tsum[tid] += t;
        __syncthreads();
    }
    int ex = tsum[tid] - mysum;
    lofs[tid * 4]     = ex;
    lofs[tid * 4 + 1] = ex + s0;
    lofs[tid * 4 + 2] = ex + s0 + s1;
    lofs[tid * 4 + 3] = ex + s0 + s1 + s2;
    __syncthreads();

    // reserve global space per touched bucket; init cursors
    for (int b = tid; b < NB; b += 256) {
        int c = lofs[b + 1] - lofs[b];
        gbase[b] = (c > 0) ? atomicAdd(&cursor[b], c) : 0;
        lcur[b]  = lofs[b];
    }
    __syncthreads();

    // group into lbuf (bucket-contiguous)
#pragma unroll
    for (int i = 0; i < EPT; ++i) {
        if (pk[i] != 0xFFFFFFFFu) {
            unsigned bk = pk[i] >> 22;
            int p = atomicAdd(&lcur[bk], 1);
            lbuf[p] = make_int2((int)pk[i], __float_as_int(pv[i]));
        }
    }
    __syncthreads();

    // write bucket-contiguous runs
    for (int j = tid; j < n; j += 256) {
        int2 cv = lbuf[j];
        unsigned bk = ((unsigned)cv.x) >> 22;
        int loc = gbase[bk] + (j - lofs[bk]);
        if (loc < CAP) {
            part[(size_t)bk * CAP + loc] = make_int2(cv.x & 0x3FFFFF, cv.y);
        } else {
            int op = atomicAdd(ovcnt, 1);
            if (op < OV_CAP) {
                int r = (int)(bk * BUCKET_SZ) + ((cv.x >> 16) & 63);
                ovbuf[op] = make_int4(r, cv.x & 0xFFFF, cv.y, 0);
            }
        }
    }
}

// ---------------------------------------------------------------------------
// Linear task: 64 rows of support = x[64 rows] @ W^T + b, bf16 out via MFMA.
// ---------------------------------------------------------------------------
__device__ __forceinline__ void do_linear(
    char* smem, int bid,
    const float* __restrict__ x, const float* __restrict__ W,
    const float* __restrict__ bias, unsigned short* __restrict__ support)
{
    short* wfrag = (short*)smem;                  // 32 KB: 4 kc x 8 strips x 64 lanes x 8

    const int tid  = threadIdx.x;
    const int lane = tid & 63;
    const int wave = tid >> 6;
    const int quad = lane >> 4;
    const int l16  = lane & 15;

    int m = bid * 64 + wave * 16 + l16;
    if (m >= N_NODES) m = N_NODES - 1;
    const float* xrow = x + (size_t)m * IN_F;

    f32x4 acc[8];
#pragma unroll
    for (int s = 0; s < 8; ++s) acc[s] = (f32x4){0.f, 0.f, 0.f, 0.f};

#pragma unroll
    for (int half = 0; half < 2; ++half) {
        // stage 4 k-chunks of W fragments (2048 frags of 16 B, 8/thread)
#pragma unroll
        for (int it = 0; it < 8; ++it) {
            const int f   = it * 256 + tid;
            const int ln  = f & 63;
            const int s   = (f >> 6) & 7;
            const int kc  = f >> 9;               // 0..3
            const int row = s * 16 + (ln & 15);
            const int k0  = (half * 4 + kc) * 32 + (ln >> 4) * 8;
            const float* wp = W + (size_t)row * IN_F + k0;
            float4 b0 = *(const float4*)wp;
            float4 b1 = *(const float4*)(wp + 4);
            *(bf16x8*)(&wfrag[(size_t)f * 8]) = cvt8(b0, b1);
        }
        __syncthreads();

#pragma unroll
        for (int kc = 0; kc < 4; ++kc) {
            const int k0 = (half * 4 + kc) * 32 + quad * 8;
            float4 a0 = *(const float4*)(xrow + k0);
            float4 a1 = *(const float4*)(xrow + k0 + 4);
            bf16x8 af = cvt8(a0, a1);
            const short* bbase = &wfrag[((size_t)(kc * 8) * 64 + lane) * 8];
#pragma unroll
            for (int s = 0; s < 8; ++s) {
                bf16x8 bf = *(const bf16x8*)(bbase + (size_t)s * 64 * 8);
                acc[s] = __builtin_amdgcn_mfma_f32_16x16x32_bf16(af, bf, acc[s], 0, 0, 0);
            }
        }
        __syncthreads();
    }

    const int rowBase = bid * 64 + wave * 16 + quad * 4;
#pragma unroll
    for (int reg = 0; reg < 4; ++reg) {
        const int r = rowBase + reg;
        if (r < N_NODES) {
#pragma unroll
            for (int s = 0; s < 8; ++s) {
                const int col = s * 16 + l16;
                float v = acc[s][reg] + bias[col];
                support[(size_t)r * HIDDEN + col] = f2bf(v);
            }
        }
    }
}

// ---------------------------------------------------------------------------
// Bucket gather task (256 threads = 4 waves; wave owns 16 rows). Two-pass
// row sort in LDS, then per-row broadcast + coalesced 256 B support gather,
// register accumulate, direct float2 store. Overflow entries folded in.
// ---------------------------------------------------------------------------
__device__ __forceinline__ void do_gather(
    char* smem, int b,
    const int* __restrict__ cursor, const int2* __restrict__ part,
    const unsigned int* __restrict__ support_u32,
    const int4* __restrict__ ovbuf, int n_ov, float* __restrict__ out)
{
    int2* sbuf = (int2*)smem;                 // 10400 B
    int*  hist = (int*)(smem + 10400);        // 256 B
    int*  rp   = (int*)(smem + 10656);        // 260 B
    int*  cur  = (int*)(smem + 10928);        // 256 B

    const int tid  = threadIdx.x;
    const int n    = min(cursor[b], CAP);
    const int wave = tid >> 6;
    const int lane = tid & 63;

    if (tid < BUCKET_SZ) hist[tid] = 0;
    __syncthreads();

    // pass 1: histogram (keys only; run is L2-resident)
    const int2* pb = part + (size_t)b * CAP;
    for (int j = tid; j < n; j += 256) {
        atomicAdd(&hist[(pb[j].x >> 16) & 63], 1);
    }
    __syncthreads();

    // wave 0: 64-bin exclusive scan via one 64-wide shuffle scan
    if (tid < 64) {
        int a = hist[tid];
        int ia = a;
#pragma unroll
        for (int off = 1; off < 64; off <<= 1) {
            int t = __shfl_up(ia, off);
            if (tid >= off) ia += t;
        }
        rp[tid + 1] = ia;
        if (tid == 0) rp[0] = 0;
        cur[tid] = ia - a;
    }
    __syncthreads();

    // pass 2: place row-sorted
    for (int j = tid; j < n; j += 256) {
        int2 cv = pb[j];
        int p = atomicAdd(&cur[(cv.x >> 16) & 63], 1);
        sbuf[p] = cv;
    }
    __syncthreads();

    // wave phase: disjoint rows per wave -> no races
    const int rowLo = wave * 16;
#pragma unroll 1
    for (int r = rowLo; r < rowLo + 16; ++r) {
        const int grow = b * BUCKET_SZ + r;
        if (grow >= N_NODES) break;
        const int s = rp[r], e = rp[r + 1];
        float ax = 0.f, ay = 0.f;
        int j = s;
        for (; j + 3 < e; j += 4) {
            int2 c0 = sbuf[j],     c1 = sbuf[j + 1];
            int2 c2 = sbuf[j + 2], c3 = sbuf[j + 3];
            unsigned u0 = support_u32[(size_t)(c0.x & 0xFFFF) * 64 + lane];
            unsigned u1 = support_u32[(size_t)(c1.x & 0xFFFF) * 64 + lane];
            unsigned u2 = support_u32[(size_t)(c2.x & 0xFFFF) * 64 + lane];
            unsigned u3 = support_u32[(size_t)(c3.x & 0xFFFF) * 64 + lane];
            float v0 = __int_as_float(c0.y), v1 = __int_as_float(c1.y);
            float v2 = __int_as_float(c2.y), v3 = __int_as_float(c3.y);
            ax += v0 * bfLo(u0); ay += v0 * bfHi(u0);
            ax += v1 * bfLo(u1); ay += v1 * bfHi(u1);
            ax += v2 * bfLo(u2); ay += v2 * bfHi(u2);
            ax += v3 * bfLo(u3); ay += v3 * bfHi(u3);
        }
        for (; j < e; ++j) {
            int2 cv = sbuf[j];
            unsigned u = support_u32[(size_t)(cv.x & 0xFFFF) * 64 + lane];
            float v = __int_as_float(cv.y);
            ax += v * bfLo(u); ay += v * bfHi(u);
        }
        // overflow fixup (n_ov == 0 in practice)
        for (int t = 0; t < n_ov; ++t) {
            int4 o = ovbuf[t];
            if (o.x == grow) {
                unsigned u = support_u32[(size_t)o.y * 64 + lane];
                float v = __int_as_float(o.z);
                ax += v * bfLo(u); ay += v * bfHi(u);
            }
        }
        *(float2*)(out + (size_t)grow * HIDDEN + lane * 2) = make_float2(ax, ay);
    }
}

// ---------------------------------------------------------------------------
// Persistent cooperative mega-kernel: zero -> (partition | linear) -> gather,
// separated by grid barriers. Replaces 3 dispatches (and their drain gaps)
// with one launch.
// ---------------------------------------------------------------------------
__global__ __launch_bounds__(256, 4) void gcn_mega_kernel(
    const float* __restrict__ x, const float* __restrict__ W,
    const float* __restrict__ bias, unsigned short* __restrict__ support,
    const int* __restrict__ adj_row, const int* __restrict__ adj_col,
    const float* __restrict__ adj_val, int* __restrict__ cursor,
    int2* __restrict__ part, int4* __restrict__ ovbuf, int* __restrict__ ovcnt,
    float* __restrict__ out)
{
    __shared__ __align__(16) char smem[SMEM_BYTES];
    cg::grid_group grid = cg::this_grid();

    // phase 0: zero cursors + ovcnt (contiguous NB+1 ints)
    if (blockIdx.x == 0) {
        for (int i = threadIdx.x; i < NB + 1; i += 256) cursor[i] = 0;
    }
    grid.sync();

    // phase 1: partition + linear tasks
    for (int task = blockIdx.x; task < NTASKS; task += gridDim.x) {
        if (task < EBLOCKS)
            do_partition(smem, task, adj_row, adj_col, adj_val, cursor, part, ovbuf, ovcnt);
        else
            do_linear(smem, task - EBLOCKS, x, W, bias, support);
        __syncthreads();
    }
    grid.sync();

    // phase 2: gather
    const int n_ov = min(*ovcnt, OV_CAP);
    for (int b = blockIdx.x; b < NB; b += gridDim.x) {
        do_gather(smem, b, cursor, part, (const unsigned int*)support, ovbuf, n_ov, out);
        __syncthreads();
    }
}

// ---------------------------------------------------------------------------
// Fallback path (identical math, 3 dispatches) in case the cooperative
// launch is rejected (capacity / capture support).
// ---------------------------------------------------------------------------
__global__ __launch_bounds__(256) void fused_linear_partition_kernel(
    const float* __restrict__ x, const float* __restrict__ W,
    const float* __restrict__ bias, unsigned short* __restrict__ support,
    const int* __restrict__ adj_row, const int* __restrict__ adj_col,
    const float* __restrict__ adj_val, int* __restrict__ cursor,
    int2* __restrict__ part, int4* __restrict__ ovbuf, int* __restrict__ ovcnt)
{
    __shared__ __align__(16) char smem[SMEM_BYTES];
    if (blockIdx.x < EBLOCKS)
        do_partition(smem, blockIdx.x, adj_row, adj_col, adj_val, cursor, part, ovbuf, ovcnt);
    else
        do_linear(smem, blockIdx.x - EBLOCKS, x, W, bias, support);
}

__global__ __launch_bounds__(256) void bucket_gather_kernel(
    const int* __restrict__ cursor, const int2* __restrict__ part,
    const unsigned int* __restrict__ support_u32,
    const int4* __restrict__ ovbuf, const int* __restrict__ ovcnt,
    float* __restrict__ out)
{
    __shared__ __align__(16) char smem[SMEM_BYTES];
    const int n_ov = min(*ovcnt, OV_CAP);
    do_gather(smem, blockIdx.x, cursor, part, support_u32, ovbuf, n_ov, out);
}

extern "C" void kernel_launch(void* const* d_in, const int* in_sizes, int n_in,
                              void* d_out, int out_size, void* d_ws, size_t ws_size,
                              hipStream_t stream) {
    const float* x       = (const float*)d_in[0];
    const int*   adj_row = (const int*)d_in[1];
    const int*   adj_col = (const int*)d_in[2];
    const float* adj_val = (const float*)d_in[3];
    const float* W       = (const float*)d_in[4];
    const float* b       = (const float*)d_in[5];
    float* out = (float*)d_out;

    char* wsb = (char*)d_ws;
    const size_t off_support = 0;                                         // 12.8 MB bf16
    const size_t off_part    = off_support + (size_t)N_NODES * HIDDEN * 2;
    const size_t off_cursor  = off_part + (size_t)NB * CAP * 8;           // 8.13 MB
    const size_t off_ovcnt   = off_cursor + (size_t)NB * 4;               // MUST stay contiguous with cursor
    const size_t off_ovbuf   = (off_ovcnt + 4 + 15) & ~(size_t)15;

    unsigned short* support = (unsigned short*)(wsb + off_support);
    int2* part   = (int2*)(wsb + off_part);
    int*  cursor = (int*)(wsb + off_cursor);
    int*  ovcnt  = (int*)(wsb + off_ovcnt);
    int4* ovbuf  = (int4*)(wsb + off_ovbuf);

    // cooperative grid size: co-resident capacity, capped at MEGA_MAXG
    static int G = 0;
    if (G == 0) {
        int nb = 0;
        if (hipOccupancyMaxActiveBlocksPerMultiprocessor(&nb, gcn_mega_kernel, 256, 0) != hipSuccess || nb < 1)
            nb = 1;
        long g = (long)nb * 256;                  // 256 CUs
        G = (g > MEGA_MAXG) ? MEGA_MAXG : (int)g;
    }

    void* args[] = {
        (void*)&x, (void*)&W, (void*)&b, (void*)&support,
        (void*)&adj_row, (void*)&adj_col, (void*)&adj_val,
        (void*)&cursor, (void*)&part, (void*)&ovbuf, (void*)&ovcnt, (void*)&out
    };
    hipError_t err = hipLaunchCooperativeKernel((const void*)gcn_mega_kernel,
                                                dim3(G), dim3(256), args, 0, stream);
    if (err != hipSuccess) {
        // fallback: classic 3-dispatch pipeline
        hipMemsetAsync(cursor, 0, (size_t)(NB + 1) * 4, stream);
        fused_linear_partition_kernel<<<NTASKS, 256, 0, stream>>>(
            x, W, b, support, adj_row, adj_col, adj_val, cursor, part, ovbuf, ovcnt);
        bucket_gather_kernel<<<NB, 256, 0, stream>>>(
            cursor, part, (const unsigned int*)support, ovbuf, ovcnt, out);
    }
}

// Round 4
// 159.587 us; speedup vs baseline: 1.9984x; 1.9984x over previous
//
#include <hip/hip_runtime.h>

#define N_NODES 50000
#define N_EDGES 800000
#define IN_F    256
#define HIDDEN  128

#define BUCKET_SZ 64                      // rows per bucket
#define NB        782                     // ceil(N_NODES / 64)
#define NBINS     1024                    // padded scan width (4 per thread x 256)
#define EBLOCK    3328                    // edges per partition task (13 x 256)
#define EPT       13                      // edges per thread
#define EBLOCKS   241                     // ceil(800000 / 3328)
#define LIN_ROWS  128                     // rows per linear task
#define LBLOCKS   391                     // ceil(50000 / 128)
#define NTASKS    632                     // EBLOCKS + LBLOCKS
#define OFSP      784                     // padded offsets row (783 used)
#define CAP       1300                    // max entries per bucket in LDS (mean 1024, +8.6 sigma)

// fused-kernel LDS union: partition 35840 B; linear 32768 B.
#define SMEM_BYTES 35840

typedef __attribute__((ext_vector_type(8))) short bf16x8;
typedef __attribute__((ext_vector_type(4))) float f32x4;

__device__ inline unsigned short f2bf(float f) {
    unsigned u = __float_as_uint(f);
    u += 0x7FFF + ((u >> 16) & 1);          // round-to-nearest-even
    return (unsigned short)(u >> 16);
}
__device__ inline bf16x8 cvt8(float4 a, float4 b) {
    bf16x8 r;
    r[0] = (short)f2bf(a.x); r[1] = (short)f2bf(a.y);
    r[2] = (short)f2bf(a.z); r[3] = (short)f2bf(a.w);
    r[4] = (short)f2bf(b.x); r[5] = (short)f2bf(b.y);
    r[6] = (short)f2bf(b.z); r[7] = (short)f2bf(b.w);
    return r;
}
__device__ inline float bfLo(unsigned u) { return __uint_as_float(u << 16); }
__device__ inline float bfHi(unsigned u) { return __uint_as_float(u & 0xFFFF0000u); }

// ---------------------------------------------------------------------------
// Fused kernel. Blocks [0, EBLOCKS): edge partition — DETERMINISTIC layout:
// task t bucket-sorts its 3328 edges into part[t*EBLOCK ..] and writes its
// 783-int offsets row ofs[t][0..782] (ofs[t][NB] = task edge count). No
// global atomics, no overflow path, no cursor memset needed.
// Blocks [EBLOCKS, NTASKS): linear — 128 rows of support = x @ W^T + b via
// MFMA bf16, staging W in LDS (2 halves), 2 row-groups per wave.
// Entry format in part: x = (row-in-bucket << 16) | col, y = f32 edge weight.
// ---------------------------------------------------------------------------
__global__ __launch_bounds__(256) void fused_linear_partition_kernel(
    const float* __restrict__ x, const float* __restrict__ W,
    const float* __restrict__ bias, unsigned short* __restrict__ support,
    const int* __restrict__ adj_row, const int* __restrict__ adj_col,
    const float* __restrict__ adj_val,
    int2* __restrict__ part, int* __restrict__ ofs)
{
    __shared__ __align__(16) char smem[SMEM_BYTES];
    const int tid = threadIdx.x;

    if (blockIdx.x < EBLOCKS) {
        // ================= PARTITION branch =================
        int2* lbuf = (int2*)smem;                    // 26624 B (3328 entries)
        int*  lofs = (int*)(smem + 26624);           // 4096 B (counts -> excl offsets)
        int*  lcur = (int*)(smem + 30720);           // 4096 B
        int*  tsum = (int*)(smem + 34816);           // 1024 B

        const int task = blockIdx.x;
        const int base = task * EBLOCK;
        const int n    = min(EBLOCK, N_EDGES - base);

        for (int i = tid; i < NBINS; i += 256) lofs[i] = 0;
        __syncthreads();

        unsigned pk[EPT]; float pv[EPT];
#pragma unroll
        for (int i = 0; i < EPT; ++i) {
            int li = tid + i * 256;
            bool ok = li < n;
            int ee = ok ? (base + li) : base;
            int r = adj_row[ee], c = adj_col[ee];
            float v = adj_val[ee];
            if (ok) {
                unsigned bk = (unsigned)r >> 6;
                pk[i] = (bk << 22) | (((unsigned)r & 63u) << 16) | (unsigned)c;
                pv[i] = v;
                atomicAdd(&lofs[bk], 1);
            } else pk[i] = 0xFFFFFFFFu;
        }
        __syncthreads();

        // exclusive scan over 1024 bins: 4 per thread + Hillis-Steele over 256
        int s0 = lofs[tid * 4], s1 = lofs[tid * 4 + 1];
        int s2 = lofs[tid * 4 + 2], s3 = lofs[tid * 4 + 3];
        int mysum = s0 + s1 + s2 + s3;
        tsum[tid] = mysum;
        __syncthreads();
#pragma unroll
        for (int off = 1; off < 256; off <<= 1) {
            int t = (tid >= off) ? tsum[tid - off] : 0;
            __syncthreads();
            tsum[tid] += t;
            __syncthreads();
        }
        int ex = tsum[tid] - mysum;
        lofs[tid * 4]     = ex;
        lofs[tid * 4 + 1] = ex + s0;
        lofs[tid * 4 + 2] = ex + s0 + s1;
        lofs[tid * 4 + 3] = ex + s0 + s1 + s2;
        __syncthreads();

        // init scatter cursors
        for (int i = tid; i < NBINS; i += 256) lcur[i] = lofs[i];
        __syncthreads();

        // group into lbuf (bucket-contiguous)
#pragma unroll
        for (int i = 0; i < EPT; ++i) {
            if (pk[i] != 0xFFFFFFFFu) {
                unsigned bk = pk[i] >> 22;
                int p = atomicAdd(&lcur[bk], 1);
                lbuf[p] = make_int2((int)(pk[i] & 0x3FFFFF), __float_as_int(pv[i]));
            }
        }
        __syncthreads();

        // write run data (coalesced) + offsets row (lofs[NB] == n)
        for (int j = tid; j < n; j += 256)
            part[(size_t)task * EBLOCK + j] = lbuf[j];
        for (int i = tid; i <= NB; i += 256)
            ofs[(size_t)task * OFSP + i] = lofs[i];
    } else {
        // ================= LINEAR branch (128 rows) =================
        short* wfrag = (short*)smem;                  // 32 KB: 4 kc x 8 strips x 64 lanes x 8

        const int bid  = blockIdx.x - EBLOCKS;
        const int lane = tid & 63;
        const int wave = tid >> 6;
        const int quad = lane >> 4;
        const int l16  = lane & 15;

        int m0 = bid * LIN_ROWS + wave * 32 + l16;        // row-group 0
        int m1 = m0 + 16;                                 // row-group 1
        if (m0 >= N_NODES) m0 = N_NODES - 1;
        if (m1 >= N_NODES) m1 = N_NODES - 1;
        const float* xr0 = x + (size_t)m0 * IN_F;
        const float* xr1 = x + (size_t)m1 * IN_F;

        f32x4 acc[2][8];
#pragma unroll
        for (int g = 0; g < 2; ++g)
#pragma unroll
            for (int s = 0; s < 8; ++s) acc[g][s] = (f32x4){0.f, 0.f, 0.f, 0.f};

#pragma unroll
        for (int half = 0; half < 2; ++half) {
            // stage 4 k-chunks of W fragments (2048 frags of 16 B, 8/thread)
#pragma unroll
            for (int it = 0; it < 8; ++it) {
                const int f   = it * 256 + tid;
                const int ln  = f & 63;
                const int s   = (f >> 6) & 7;
                const int kc  = f >> 9;               // 0..3
                const int row = s * 16 + (ln & 15);
                const int k0  = (half * 4 + kc) * 32 + (ln >> 4) * 8;
                const float* wp = W + (size_t)row * IN_F + k0;
                float4 b0 = *(const float4*)wp;
                float4 b1 = *(const float4*)(wp + 4);
                *(bf16x8*)(&wfrag[(size_t)f * 8]) = cvt8(b0, b1);
            }
            __syncthreads();

#pragma unroll
            for (int kc = 0; kc < 4; ++kc) {
                const int k0 = (half * 4 + kc) * 32 + quad * 8;
                float4 a0 = *(const float4*)(xr0 + k0);
                float4 a1 = *(const float4*)(xr0 + k0 + 4);
                bf16x8 af0 = cvt8(a0, a1);
                float4 a2 = *(const float4*)(xr1 + k0);
                float4 a3 = *(const float4*)(xr1 + k0 + 4);
                bf16x8 af1 = cvt8(a2, a3);
                const short* bbase = &wfrag[((size_t)(kc * 8) * 64 + lane) * 8];
#pragma unroll
                for (int s = 0; s < 8; ++s) {
                    bf16x8 bf = *(const bf16x8*)(bbase + (size_t)s * 64 * 8);
                    acc[0][s] = __builtin_amdgcn_mfma_f32_16x16x32_bf16(af0, bf, acc[0][s], 0, 0, 0);
                    acc[1][s] = __builtin_amdgcn_mfma_f32_16x16x32_bf16(af1, bf, acc[1][s], 0, 0, 0);
                }
            }
            __syncthreads();
        }

#pragma unroll
        for (int g = 0; g < 2; ++g) {
            const int rowBase = bid * LIN_ROWS + wave * 32 + g * 16 + quad * 4;
#pragma unroll
            for (int reg = 0; reg < 4; ++reg) {
                const int r = rowBase + reg;
                if (r < N_NODES) {
#pragma unroll
                    for (int s = 0; s < 8; ++s) {
                        const int col = s * 16 + l16;
                        float v = acc[g][s][reg] + bias[col];
                        support[(size_t)r * HIDDEN + col] = f2bf(v);
                    }
                }
            }
        }
    }
}

// ---------------------------------------------------------------------------
// Bucket gather: 512 threads per 64-row bucket. Thread t (< EBLOCKS) copies
// task t's segment for this bucket into LDS (one global walk over part),
// then LDS histogram -> 64-wide scan -> LDS permute row-sorted, then the
// accumulate phase: wave w owns rows [8w, 8w+8), coalesced 256 B support
// gathers, register accumulate, direct float2 store. No atomics to global.
// ---------------------------------------------------------------------------
__global__ __launch_bounds__(512) void bucket_gather_kernel(
    const int* __restrict__ ofs, const int2* __restrict__ part,
    const unsigned int* __restrict__ support_u32, float* __restrict__ out)
{
    __shared__ int2 sbufA[CAP];               // 10400 B (unsorted)
    __shared__ int2 sbufB[CAP];               // 10400 B (row-sorted)
    __shared__ int  sarr[512];
    __shared__ int  hist[BUCKET_SZ];
    __shared__ int  rp[BUCKET_SZ + 1];
    __shared__ int  cur[BUCKET_SZ];

    const int tid  = threadIdx.x;
    const int b    = blockIdx.x;
    const int wave = tid >> 6;
    const int lane = tid & 63;

    if (tid < BUCKET_SZ) hist[tid] = 0;

    // segment for task tid in bucket b
    int sstart = 0, slen = 0;
    if (tid < EBLOCKS) {
        const int* orow = ofs + (size_t)tid * OFSP + b;
        sstart = orow[0];
        slen   = orow[1] - sstart;
    }
    sarr[tid] = slen;
    __syncthreads();

    // inclusive scan over 512 (Hillis-Steele)
#pragma unroll
    for (int off = 1; off < 512; off <<= 1) {
        int t = (tid >= off) ? sarr[tid - off] : 0;
        __syncthreads();
        sarr[tid] += t;
        __syncthreads();
    }
    const int excl = sarr[tid] - slen;
    const int n    = min(sarr[511], CAP);

    // copy segment into LDS (ragged; segments are contiguous in part)
    {
        const int2* seg = part + (size_t)tid * EBLOCK + sstart;
        for (int k = 0; k < slen; ++k) {
            int p = excl + k;
            if (p < CAP) sbufA[p] = seg[k];
        }
    }
    __syncthreads();

    // histogram over row-in-bucket
    for (int j = tid; j < n; j += 512)
        atomicAdd(&hist[(sbufA[j].x >> 16) & 63], 1);
    __syncthreads();

    // wave 0: 64-bin exclusive scan via one 64-wide shuffle scan
    if (tid < 64) {
        int a = hist[tid];
        int ia = a;
#pragma unroll
        for (int off = 1; off < 64; off <<= 1) {
            int t = __shfl_up(ia, off);
            if (tid >= off) ia += t;
        }
        rp[tid + 1] = ia;
        if (tid == 0) rp[0] = 0;
        cur[tid] = ia - a;
    }
    __syncthreads();

    // place row-sorted
    for (int j = tid; j < n; j += 512) {
        int2 cv = sbufA[j];
        int p = atomicAdd(&cur[(cv.x >> 16) & 63], 1);
        sbufB[p] = cv;
    }
    __syncthreads();

    // accumulate: disjoint rows per wave -> no races
    const int rowLo = wave * 8;
#pragma unroll 1
    for (int r = rowLo; r < rowLo + 8; ++r) {
        const int grow = b * BUCKET_SZ + r;
        if (grow >= N_NODES) break;
        const int s = rp[r], e = rp[r + 1];
        float ax = 0.f, ay = 0.f;
        int j = s;
        for (; j + 3 < e; j += 4) {
            int2 c0 = sbufB[j],     c1 = sbufB[j + 1];
            int2 c2 = sbufB[j + 2], c3 = sbufB[j + 3];
            unsigned u0 = support_u32[(size_t)(c0.x & 0xFFFF) * 64 + lane];
            unsigned u1 = support_u32[(size_t)(c1.x & 0xFFFF) * 64 + lane];
            unsigned u2 = support_u32[(size_t)(c2.x & 0xFFFF) * 64 + lane];
            unsigned u3 = support_u32[(size_t)(c3.x & 0xFFFF) * 64 + lane];
            float v0 = __int_as_float(c0.y), v1 = __int_as_float(c1.y);
            float v2 = __int_as_float(c2.y), v3 = __int_as_float(c3.y);
            ax += v0 * bfLo(u0); ay += v0 * bfHi(u0);
            ax += v1 * bfLo(u1); ay += v1 * bfHi(u1);
            ax += v2 * bfLo(u2); ay += v2 * bfHi(u2);
            ax += v3 * bfLo(u3); ay += v3 * bfHi(u3);
        }
        for (; j < e; ++j) {
            int2 cv = sbufB[j];
            unsigned u = support_u32[(size_t)(cv.x & 0xFFFF) * 64 + lane];
            float v = __int_as_float(cv.y);
            ax += v * bfLo(u); ay += v * bfHi(u);
        }
        *(float2*)(out + (size_t)grow * HIDDEN + lane * 2) = make_float2(ax, ay);
    }
}

extern "C" void kernel_launch(void* const* d_in, const int* in_sizes, int n_in,
                              void* d_out, int out_size, void* d_ws, size_t ws_size,
                              hipStream_t stream) {
    const float* x       = (const float*)d_in[0];
    const int*   adj_row = (const int*)d_in[1];
    const int*   adj_col = (const int*)d_in[2];
    const float* adj_val = (const float*)d_in[3];
    const float* W       = (const float*)d_in[4];
    const float* b       = (const float*)d_in[5];
    float* out = (float*)d_out;

    char* wsb = (char*)d_ws;
    const size_t off_support = 0;                                          // 12.8 MB bf16
    const size_t off_part    = off_support + (size_t)N_NODES * HIDDEN * 2;
    const size_t off_ofs     = off_part + (size_t)EBLOCKS * EBLOCK * 8;    // 6.42 MB
    // ofs: 0.76 MB; total ~20.0 MB

    unsigned short* support = (unsigned short*)(wsb + off_support);
    int2* part = (int2*)(wsb + off_part);
    int*  ofs  = (int*)(wsb + off_ofs);

    fused_linear_partition_kernel<<<NTASKS, 256, 0, stream>>>(
        x, W, b, support, adj_row, adj_col, adj_val, part, ofs);
    bucket_gather_kernel<<<NB, 512, 0, stream>>>(
        ofs, part, (const unsigned int*)support, out);
}

// Round 5
// 158.985 us; speedup vs baseline: 2.0060x; 1.0038x over previous
//
#include <hip/hip_runtime.h>

#define N_NODES 50000
#define N_EDGES 800000
#define IN_F    256
#define HIDDEN  128

#define BUCKET_SZ 64                      // rows per bucket
#define NB        782                     // ceil(N_NODES / 64)
#define NBINS     1024                    // padded scan width (4 per thread x 256)
#define EBLOCK    3328                    // edges per partition task (13 x 256)
#define EPT       13                      // edges per thread
#define EBLOCKS   241                     // ceil(800000 / 3328)
#define LIN_ROWS  128                     // rows per linear task
#define LBLOCKS   391                     // ceil(50000 / 128)
#define NTASKS    632                     // EBLOCKS + LBLOCKS
#define OFST_W    256                     // ofsT row width (241 used, padded)
#define CAP       1300                    // max entries per bucket in LDS (mean 1024, +8.6 sigma)

// fused-kernel LDS union: partition 35840 B; linear 32768 B.
#define SMEM_BYTES 35840

typedef __attribute__((ext_vector_type(8))) short bf16x8;
typedef __attribute__((ext_vector_type(4))) float f32x4;

__device__ inline unsigned short f2bf(float f) {
    unsigned u = __float_as_uint(f);
    u += 0x7FFF + ((u >> 16) & 1);          // round-to-nearest-even
    return (unsigned short)(u >> 16);
}
__device__ inline bf16x8 cvt8(float4 a, float4 b) {
    bf16x8 r;
    r[0] = (short)f2bf(a.x); r[1] = (short)f2bf(a.y);
    r[2] = (short)f2bf(a.z); r[3] = (short)f2bf(a.w);
    r[4] = (short)f2bf(b.x); r[5] = (short)f2bf(b.y);
    r[6] = (short)f2bf(b.z); r[7] = (short)f2bf(b.w);
    return r;
}
__device__ inline float bfLo(unsigned u) { return __uint_as_float(u << 16); }
__device__ inline float bfHi(unsigned u) { return __uint_as_float(u & 0xFFFF0000u); }

// ---------------------------------------------------------------------------
// Fused kernel. Blocks [0, EBLOCKS): edge partition — deterministic layout:
// task t bucket-sorts its 3328 edges into part[t*EBLOCK ..] and writes its
// offsets TRANSPOSED: ofsT[i][t] = lofs_t[i] for i in [0, NB]. The transpose
// makes the gather kernel's offset reads coalesced (one row per bucket).
// Blocks [EBLOCKS, NTASKS): linear — 128 rows of support = x @ W^T + b via
// MFMA bf16, staging W in LDS (2 halves), 2 row-groups per wave.
// Entry format in part: x = (row-in-bucket << 16) | col, y = f32 edge weight.
// ---------------------------------------------------------------------------
__global__ __launch_bounds__(256) void fused_linear_partition_kernel(
    const float* __restrict__ x, const float* __restrict__ W,
    const float* __restrict__ bias, unsigned short* __restrict__ support,
    const int* __restrict__ adj_row, const int* __restrict__ adj_col,
    const float* __restrict__ adj_val,
    int2* __restrict__ part, int* __restrict__ ofsT)
{
    __shared__ __align__(16) char smem[SMEM_BYTES];
    const int tid = threadIdx.x;

    if (blockIdx.x < EBLOCKS) {
        // ================= PARTITION branch =================
        int2* lbuf = (int2*)smem;                    // 26624 B (3328 entries)
        int*  lofs = (int*)(smem + 26624);           // 4096 B (counts -> excl offsets)
        int*  lcur = (int*)(smem + 30720);           // 4096 B
        int*  tsum = (int*)(smem + 34816);           // 1024 B

        const int task = blockIdx.x;
        const int base = task * EBLOCK;
        const int n    = min(EBLOCK, N_EDGES - base);

        for (int i = tid; i < NBINS; i += 256) lofs[i] = 0;
        __syncthreads();

        unsigned pk[EPT]; float pv[EPT];
#pragma unroll
        for (int i = 0; i < EPT; ++i) {
            int li = tid + i * 256;
            bool ok = li < n;
            int ee = ok ? (base + li) : base;
            int r = adj_row[ee], c = adj_col[ee];
            float v = adj_val[ee];
            if (ok) {
                unsigned bk = (unsigned)r >> 6;
                pk[i] = (bk << 22) | (((unsigned)r & 63u) << 16) | (unsigned)c;
                pv[i] = v;
                atomicAdd(&lofs[bk], 1);
            } else pk[i] = 0xFFFFFFFFu;
        }
        __syncthreads();

        // exclusive scan over 1024 bins: 4 per thread + Hillis-Steele over 256
        int s0 = lofs[tid * 4], s1 = lofs[tid * 4 + 1];
        int s2 = lofs[tid * 4 + 2], s3 = lofs[tid * 4 + 3];
        int mysum = s0 + s1 + s2 + s3;
        tsum[tid] = mysum;
        __syncthreads();
#pragma unroll
        for (int off = 1; off < 256; off <<= 1) {
            int t = (tid >= off) ? tsum[tid - off] : 0;
            __syncthreads();
            tsum[tid] += t;
            __syncthreads();
        }
        int ex = tsum[tid] - mysum;
        lofs[tid * 4]     = ex;
        lofs[tid * 4 + 1] = ex + s0;
        lofs[tid * 4 + 2] = ex + s0 + s1;
        lofs[tid * 4 + 3] = ex + s0 + s1 + s2;
        __syncthreads();

        // init scatter cursors
        for (int i = tid; i < NBINS; i += 256) lcur[i] = lofs[i];
        __syncthreads();

        // group into lbuf (bucket-contiguous)
#pragma unroll
        for (int i = 0; i < EPT; ++i) {
            if (pk[i] != 0xFFFFFFFFu) {
                unsigned bk = pk[i] >> 22;
                int p = atomicAdd(&lcur[bk], 1);
                lbuf[p] = make_int2((int)(pk[i] & 0x3FFFFF), __float_as_int(pv[i]));
            }
        }
        __syncthreads();

        // write run data (coalesced) + transposed offsets column
        for (int j = tid; j < n; j += 256)
            part[(size_t)task * EBLOCK + j] = lbuf[j];
        for (int i = tid; i <= NB; i += 256)
            ofsT[(size_t)i * OFST_W + task] = lofs[i];
    } else {
        // ================= LINEAR branch (128 rows) =================
        short* wfrag = (short*)smem;                  // 32 KB: 4 kc x 8 strips x 64 lanes x 8

        const int bid  = blockIdx.x - EBLOCKS;
        const int lane = tid & 63;
        const int wave = tid >> 6;
        const int quad = lane >> 4;
        const int l16  = lane & 15;

        int m0 = bid * LIN_ROWS + wave * 32 + l16;        // row-group 0
        int m1 = m0 + 16;                                 // row-group 1
        if (m0 >= N_NODES) m0 = N_NODES - 1;
        if (m1 >= N_NODES) m1 = N_NODES - 1;
        const float* xr0 = x + (size_t)m0 * IN_F;
        const float* xr1 = x + (size_t)m1 * IN_F;

        f32x4 acc[2][8];
#pragma unroll
        for (int g = 0; g < 2; ++g)
#pragma unroll
            for (int s = 0; s < 8; ++s) acc[g][s] = (f32x4){0.f, 0.f, 0.f, 0.f};

#pragma unroll
        for (int half = 0; half < 2; ++half) {
            // stage 4 k-chunks of W fragments (2048 frags of 16 B, 8/thread)
#pragma unroll
            for (int it = 0; it < 8; ++it) {
                const int f   = it * 256 + tid;
                const int ln  = f & 63;
                const int s   = (f >> 6) & 7;
                const int kc  = f >> 9;               // 0..3
                const int row = s * 16 + (ln & 15);
                const int k0  = (half * 4 + kc) * 32 + (ln >> 4) * 8;
                const float* wp = W + (size_t)row * IN_F + k0;
                float4 b0 = *(const float4*)wp;
                float4 b1 = *(const float4*)(wp + 4);
                *(bf16x8*)(&wfrag[(size_t)f * 8]) = cvt8(b0, b1);
            }
            __syncthreads();

#pragma unroll
            for (int kc = 0; kc < 4; ++kc) {
                const int k0 = (half * 4 + kc) * 32 + quad * 8;
                float4 a0 = *(const float4*)(xr0 + k0);
                float4 a1 = *(const float4*)(xr0 + k0 + 4);
                bf16x8 af0 = cvt8(a0, a1);
                float4 a2 = *(const float4*)(xr1 + k0);
                float4 a3 = *(const float4*)(xr1 + k0 + 4);
                bf16x8 af1 = cvt8(a2, a3);
                const short* bbase = &wfrag[((size_t)(kc * 8) * 64 + lane) * 8];
#pragma unroll
                for (int s = 0; s < 8; ++s) {
                    bf16x8 bf = *(const bf16x8*)(bbase + (size_t)s * 64 * 8);
                    acc[0][s] = __builtin_amdgcn_mfma_f32_16x16x32_bf16(af0, bf, acc[0][s], 0, 0, 0);
                    acc[1][s] = __builtin_amdgcn_mfma_f32_16x16x32_bf16(af1, bf, acc[1][s], 0, 0, 0);
                }
            }
            __syncthreads();
        }

#pragma unroll
        for (int g = 0; g < 2; ++g) {
            const int rowBase = bid * LIN_ROWS + wave * 32 + g * 16 + quad * 4;
#pragma unroll
            for (int reg = 0; reg < 4; ++reg) {
                const int r = rowBase + reg;
                if (r < N_NODES) {
#pragma unroll
                    for (int s = 0; s < 8; ++s) {
                        const int col = s * 16 + l16;
                        float v = acc[g][s][reg] + bias[col];
                        support[(size_t)r * HIDDEN + col] = f2bf(v);
                    }
                }
            }
        }
    }
}

// ---------------------------------------------------------------------------
// Bucket gather: 512 threads per 64-row bucket.
//  - coalesced ofsT row reads (transposed offsets)
//  - 1-barrier wave-shuffle scan of per-task segment lengths
//  - copy+histogram fused (one pass over segments)
//  - LDS permute row-sorted, then accumulate: wave w owns rows [8w,8w+8),
//    8-deep unrolled coalesced 256 B support gathers, register accumulate,
//    direct float2 store. No global atomics anywhere.
// ---------------------------------------------------------------------------
__global__ __launch_bounds__(512) void bucket_gather_kernel(
    const int* __restrict__ ofsT, const int2* __restrict__ part,
    const unsigned int* __restrict__ support_u32, float* __restrict__ out)
{
    __shared__ int2 sbufA[CAP];               // 10400 B (unsorted)
    __shared__ int2 sbufB[CAP];               // 10400 B (row-sorted)
    __shared__ int  wsum[8];
    __shared__ int  hist[BUCKET_SZ];
    __shared__ int  rp[BUCKET_SZ + 1];
    __shared__ int  cur[BUCKET_SZ];

    const int tid  = threadIdx.x;
    const int b    = blockIdx.x;
    const int wave = tid >> 6;
    const int lane = tid & 63;

    if (tid < BUCKET_SZ) hist[tid] = 0;

    // coalesced segment offsets for this bucket: rows b and b+1 of ofsT
    int s0 = 0, slen = 0;
    if (tid < EBLOCKS) {
        s0   = ofsT[(size_t)b * OFST_W + tid];
        slen = ofsT[(size_t)(b + 1) * OFST_W + tid] - s0;
    }

    // exclusive prefix of slen over 512 threads: per-wave shfl scan + combine
    int iv = slen;
#pragma unroll
    for (int off = 1; off < 64; off <<= 1) {
        int t = __shfl_up(iv, off);
        if (lane >= off) iv += t;
    }
    if (lane == 63) wsum[wave] = iv;
    __syncthreads();
    int wpre = 0, total = 0;
#pragma unroll
    for (int w = 0; w < 8; ++w) {
        int sw = wsum[w];
        total += sw;
        if (w < wave) wpre += sw;
    }
    const int excl = wpre + iv - slen;
    const int n    = min(total, CAP);

    // copy segment into LDS + histogram (fused, one pass)
    {
        const int2* seg = part + (size_t)tid * EBLOCK + s0;
        for (int k = 0; k < slen; ++k) {
            int p = excl + k;
            if (p < CAP) {
                int2 cv = seg[k];
                sbufA[p] = cv;
                atomicAdd(&hist[(cv.x >> 16) & 63], 1);
            }
        }
    }
    __syncthreads();

    // wave 0: 64-bin exclusive scan via one 64-wide shuffle scan
    if (tid < 64) {
        int a = hist[tid];
        int ia = a;
#pragma unroll
        for (int off = 1; off < 64; off <<= 1) {
            int t = __shfl_up(ia, off);
            if (tid >= off) ia += t;
        }
        rp[tid + 1] = ia;
        if (tid == 0) rp[0] = 0;
        cur[tid] = ia - a;
    }
    __syncthreads();

    // place row-sorted
    for (int j = tid; j < n; j += 512) {
        int2 cv = sbufA[j];
        int p = atomicAdd(&cur[(cv.x >> 16) & 63], 1);
        sbufB[p] = cv;
    }
    __syncthreads();

    // accumulate: disjoint rows per wave -> no races; 8-deep ILP
    const int rowLo = wave * 8;
#pragma unroll 1
    for (int r = rowLo; r < rowLo + 8; ++r) {
        const int grow = b * BUCKET_SZ + r;
        if (grow >= N_NODES) break;
        const int s = rp[r], e = rp[r + 1];
        float ax = 0.f, ay = 0.f;
        int j = s;
        for (; j + 7 < e; j += 8) {
            int2 c0 = sbufB[j],     c1 = sbufB[j + 1];
            int2 c2 = sbufB[j + 2], c3 = sbufB[j + 3];
            int2 c4 = sbufB[j + 4], c5 = sbufB[j + 5];
            int2 c6 = sbufB[j + 6], c7 = sbufB[j + 7];
            unsigned u0 = support_u32[(size_t)(c0.x & 0xFFFF) * 64 + lane];
            unsigned u1 = support_u32[(size_t)(c1.x & 0xFFFF) * 64 + lane];
            unsigned u2 = support_u32[(size_t)(c2.x & 0xFFFF) * 64 + lane];
            unsigned u3 = support_u32[(size_t)(c3.x & 0xFFFF) * 64 + lane];
            unsigned u4 = support_u32[(size_t)(c4.x & 0xFFFF) * 64 + lane];
            unsigned u5 = support_u32[(size_t)(c5.x & 0xFFFF) * 64 + lane];
            unsigned u6 = support_u32[(size_t)(c6.x & 0xFFFF) * 64 + lane];
            unsigned u7 = support_u32[(size_t)(c7.x & 0xFFFF) * 64 + lane];
            float v0 = __int_as_float(c0.y), v1 = __int_as_float(c1.y);
            float v2 = __int_as_float(c2.y), v3 = __int_as_float(c3.y);
            float v4 = __int_as_float(c4.y), v5 = __int_as_float(c5.y);
            float v6 = __int_as_float(c6.y), v7 = __int_as_float(c7.y);
            ax += v0 * bfLo(u0); ay += v0 * bfHi(u0);
            ax += v1 * bfLo(u1); ay += v1 * bfHi(u1);
            ax += v2 * bfLo(u2); ay += v2 * bfHi(u2);
            ax += v3 * bfLo(u3); ay += v3 * bfHi(u3);
            ax += v4 * bfLo(u4); ay += v4 * bfHi(u4);
            ax += v5 * bfLo(u5); ay += v5 * bfHi(u5);
            ax += v6 * bfLo(u6); ay += v6 * bfHi(u6);
            ax += v7 * bfLo(u7); ay += v7 * bfHi(u7);
        }
        for (; j + 3 < e; j += 4) {
            int2 c0 = sbufB[j],     c1 = sbufB[j + 1];
            int2 c2 = sbufB[j + 2], c3 = sbufB[j + 3];
            unsigned u0 = support_u32[(size_t)(c0.x & 0xFFFF) * 64 + lane];
            unsigned u1 = support_u32[(size_t)(c1.x & 0xFFFF) * 64 + lane];
            unsigned u2 = support_u32[(size_t)(c2.x & 0xFFFF) * 64 + lane];
            unsigned u3 = support_u32[(size_t)(c3.x & 0xFFFF) * 64 + lane];
            float v0 = __int_as_float(c0.y), v1 = __int_as_float(c1.y);
            float v2 = __int_as_float(c2.y), v3 = __int_as_float(c3.y);
            ax += v0 * bfLo(u0); ay += v0 * bfHi(u0);
            ax += v1 * bfLo(u1); ay += v1 * bfHi(u1);
            ax += v2 * bfLo(u2); ay += v2 * bfHi(u2);
            ax += v3 * bfLo(u3); ay += v3 * bfHi(u3);
        }
        for (; j < e; ++j) {
            int2 cv = sbufB[j];
            unsigned u = support_u32[(size_t)(cv.x & 0xFFFF) * 64 + lane];
            float v = __int_as_float(cv.y);
            ax += v * bfLo(u); ay += v * bfHi(u);
        }
        *(float2*)(out + (size_t)grow * HIDDEN + lane * 2) = make_float2(ax, ay);
    }
}

extern "C" void kernel_launch(void* const* d_in, const int* in_sizes, int n_in,
                              void* d_out, int out_size, void* d_ws, size_t ws_size,
                              hipStream_t stream) {
    const float* x       = (const float*)d_in[0];
    const int*   adj_row = (const int*)d_in[1];
    const int*   adj_col = (const int*)d_in[2];
    const float* adj_val = (const float*)d_in[3];
    const float* W       = (const float*)d_in[4];
    const float* b       = (const float*)d_in[5];
    float* out = (float*)d_out;

    char* wsb = (char*)d_ws;
    const size_t off_support = 0;                                          // 12.8 MB bf16
    const size_t off_part    = off_support + (size_t)N_NODES * HIDDEN * 2;
    const size_t off_ofsT    = off_part + (size_t)EBLOCKS * EBLOCK * 8;    // 6.42 MB
    // ofsT: (NB+1) x 256 ints = 0.80 MB; total ~20.0 MB

    unsigned short* support = (unsigned short*)(wsb + off_support);
    int2* part = (int2*)(wsb + off_part);
    int*  ofsT = (int*)(wsb + off_ofsT);

    fused_linear_partition_kernel<<<NTASKS, 256, 0, stream>>>(
        x, W, b, support, adj_row, adj_col, adj_val, part, ofsT);
    bucket_gather_kernel<<<NB, 512, 0, stream>>>(
        ofsT, part, (const unsigned int*)support, out);
}

// Round 6
// 156.121 us; speedup vs baseline: 2.0428x; 1.0183x over previous
//
#include <hip/hip_runtime.h>

#define N_NODES 50000
#define N_EDGES 800000
#define IN_F    256
#define HIDDEN  128

#define BUCKET_SZ 64                      // rows per bucket
#define NB        782                     // ceil(N_NODES / 64)
#define NBINS     1024                    // padded scan width (4 per thread x 256)
#define EBLOCK    3328                    // edges per partition task (13 x 256)
#define EPT       13                      // edges per thread
#define EBLOCKS   241                     // ceil(800000 / 3328)
#define LIN_ROWS  64                      // rows per linear task
#define LBLOCKS   782                     // ceil(50000 / 64)
#define NTASKS    1023                    // EBLOCKS + LBLOCKS (= 4.0 blocks/CU)
#define OFST_W    256                     // ofsT row width (241 used, padded)
#define CAP       1300                    // max entries per bucket in LDS (mean 1024, +8.6 sigma)
#define NFRAG     4096                    // W bf16 fragments: 8 hk x 8 s x 64 lanes

// fused-kernel LDS: partition branch only (linear branch uses none).
#define SMEM_BYTES 35840

typedef __attribute__((ext_vector_type(8))) short bf16x8;
typedef __attribute__((ext_vector_type(4))) float f32x4;

__device__ inline unsigned short f2bf(float f) {
    unsigned u = __float_as_uint(f);
    u += 0x7FFF + ((u >> 16) & 1);          // round-to-nearest-even
    return (unsigned short)(u >> 16);
}
__device__ inline bf16x8 cvt8(float4 a, float4 b) {
    bf16x8 r;
    r[0] = (short)f2bf(a.x); r[1] = (short)f2bf(a.y);
    r[2] = (short)f2bf(a.z); r[3] = (short)f2bf(a.w);
    r[4] = (short)f2bf(b.x); r[5] = (short)f2bf(b.y);
    r[6] = (short)f2bf(b.z); r[7] = (short)f2bf(b.w);
    return r;
}
__device__ inline float bfLo(unsigned u) { return __uint_as_float(u << 16); }
__device__ inline float bfHi(unsigned u) { return __uint_as_float(u & 0xFFFF0000u); }

// ---------------------------------------------------------------------------
// W pre-convert: f32 W[128][256] -> bf16 MFMA B-fragments, fragment order
// wb[((hk*8 + s)*64 + lane)*8 ..] where hk = k/32 (0..7), s = col-strip
// (0..7), rows s*16+(lane&15), k = hk*32 + (lane>>4)*8. 64 KB total; runs
// once, then every linear block reads fragments straight from L2.
// ---------------------------------------------------------------------------
__global__ __launch_bounds__(256) void wconv_kernel(
    const float* __restrict__ W, unsigned short* __restrict__ wb)
{
    const int f = blockIdx.x * 256 + threadIdx.x;     // 0..4095
    if (f >= NFRAG) return;
    const int ln = f & 63;
    const int s  = (f >> 6) & 7;
    const int hk = f >> 9;
    const int row = s * 16 + (ln & 15);
    const int k0  = hk * 32 + (ln >> 4) * 8;
    const float* wp = W + (size_t)row * IN_F + k0;
    float4 b0 = *(const float4*)wp;
    float4 b1 = *(const float4*)(wp + 4);
    *(bf16x8*)(wb + (size_t)f * 8) = cvt8(b0, b1);
}

// ---------------------------------------------------------------------------
// Fused kernel. Blocks [0, EBLOCKS): edge partition — deterministic layout:
// task t bucket-sorts its 3328 edges into part[t*EBLOCK ..] and writes its
// offsets TRANSPOSED (ofsT[i][t]) so the gather's offset reads coalesce.
// Blocks [EBLOCKS, NTASKS): linear — 64 rows of support = x @ W^T + b via
// MFMA bf16. LDS-FREE: B-fragments stream from the pre-converted wb (L2-hot),
// no staging loops, no barriers. Wave w owns rows [16w, 16w+16).
// Entry format in part: x = (row-in-bucket << 16) | col, y = f32 edge weight.
// ---------------------------------------------------------------------------
__global__ __launch_bounds__(256, 4) void fused_linear_partition_kernel(
    const float* __restrict__ x, const unsigned short* __restrict__ wb,
    const float* __restrict__ bias, unsigned short* __restrict__ support,
    const int* __restrict__ adj_row, const int* __restrict__ adj_col,
    const float* __restrict__ adj_val,
    int2* __restrict__ part, int* __restrict__ ofsT)
{
    const int tid = threadIdx.x;

    if (blockIdx.x < EBLOCKS) {
        // ================= PARTITION branch =================
        __shared__ __align__(16) char smem[SMEM_BYTES];
        int2* lbuf = (int2*)smem;                    // 26624 B (3328 entries)
        int*  lofs = (int*)(smem + 26624);           // 4096 B (counts -> excl offsets)
        int*  lcur = (int*)(smem + 30720);           // 4096 B
        int*  tsum = (int*)(smem + 34816);           // 1024 B

        const int task = blockIdx.x;
        const int base = task * EBLOCK;
        const int n    = min(EBLOCK, N_EDGES - base);

        for (int i = tid; i < NBINS; i += 256) lofs[i] = 0;
        __syncthreads();

        unsigned pk[EPT]; float pv[EPT];
#pragma unroll
        for (int i = 0; i < EPT; ++i) {
            int li = tid + i * 256;
            bool ok = li < n;
            int ee = ok ? (base + li) : base;
            int r = adj_row[ee], c = adj_col[ee];
            float v = adj_val[ee];
            if (ok) {
                unsigned bk = (unsigned)r >> 6;
                pk[i] = (bk << 22) | (((unsigned)r & 63u) << 16) | (unsigned)c;
                pv[i] = v;
                atomicAdd(&lofs[bk], 1);
            } else pk[i] = 0xFFFFFFFFu;
        }
        __syncthreads();

        // exclusive scan over 1024 bins: 4 per thread + Hillis-Steele over 256
        int s0 = lofs[tid * 4], s1 = lofs[tid * 4 + 1];
        int s2 = lofs[tid * 4 + 2], s3 = lofs[tid * 4 + 3];
        int mysum = s0 + s1 + s2 + s3;
        tsum[tid] = mysum;
        __syncthreads();
#pragma unroll
        for (int off = 1; off < 256; off <<= 1) {
            int t = (tid >= off) ? tsum[tid - off] : 0;
            __syncthreads();
            tsum[tid] += t;
            __syncthreads();
        }
        int ex = tsum[tid] - mysum;
        lofs[tid * 4]     = ex;
        lofs[tid * 4 + 1] = ex + s0;
        lofs[tid * 4 + 2] = ex + s0 + s1;
        lofs[tid * 4 + 3] = ex + s0 + s1 + s2;
        __syncthreads();

        // init scatter cursors
        for (int i = tid; i < NBINS; i += 256) lcur[i] = lofs[i];
        __syncthreads();

        // group into lbuf (bucket-contiguous)
#pragma unroll
        for (int i = 0; i < EPT; ++i) {
            if (pk[i] != 0xFFFFFFFFu) {
                unsigned bk = pk[i] >> 22;
                int p = atomicAdd(&lcur[bk], 1);
                lbuf[p] = make_int2((int)(pk[i] & 0x3FFFFF), __float_as_int(pv[i]));
            }
        }
        __syncthreads();

        // write run data (coalesced) + transposed offsets column
        for (int j = tid; j < n; j += 256)
            part[(size_t)task * EBLOCK + j] = lbuf[j];
        for (int i = tid; i <= NB; i += 256)
            ofsT[(size_t)i * OFST_W + task] = lofs[i];
    } else {
        // ================= LINEAR branch (64 rows, LDS-free) =================
        const int bid  = blockIdx.x - EBLOCKS;
        const int lane = tid & 63;
        const int wave = tid >> 6;
        const int quad = lane >> 4;
        const int l16  = lane & 15;

        int m = bid * LIN_ROWS + wave * 16 + l16;
        if (m >= N_NODES) m = N_NODES - 1;
        const float* xrow = x + (size_t)m * IN_F;
        const bf16x8* wbv = (const bf16x8*)wb;

        f32x4 acc[8];
#pragma unroll
        for (int s = 0; s < 8; ++s) acc[s] = (f32x4){0.f, 0.f, 0.f, 0.f};

#pragma unroll 2
        for (int hk = 0; hk < 8; ++hk) {
            const int k0 = hk * 32 + quad * 8;
            float4 a0 = *(const float4*)(xrow + k0);
            float4 a1 = *(const float4*)(xrow + k0 + 4);
            bf16x8 af = cvt8(a0, a1);
            const bf16x8* bb = wbv + (size_t)hk * 512 + lane;
#pragma unroll
            for (int s = 0; s < 8; ++s) {
                bf16x8 bf = bb[(size_t)s * 64];
                acc[s] = __builtin_amdgcn_mfma_f32_16x16x32_bf16(af, bf, acc[s], 0, 0, 0);
            }
        }

        const int rowBase = bid * LIN_ROWS + wave * 16 + quad * 4;
#pragma unroll
        for (int reg = 0; reg < 4; ++reg) {
            const int r = rowBase + reg;
            if (r < N_NODES) {
#pragma unroll
                for (int s = 0; s < 8; ++s) {
                    const int col = s * 16 + l16;
                    float v = acc[s][reg] + bias[col];
                    support[(size_t)r * HIDDEN + col] = f2bf(v);
                }
            }
        }
    }
}

// ---------------------------------------------------------------------------
// Bucket gather: 512 threads per 64-row bucket (unchanged from round 5).
// ---------------------------------------------------------------------------
__global__ __launch_bounds__(512) void bucket_gather_kernel(
    const int* __restrict__ ofsT, const int2* __restrict__ part,
    const unsigned int* __restrict__ support_u32, float* __restrict__ out)
{
    __shared__ int2 sbufA[CAP];               // 10400 B (unsorted)
    __shared__ int2 sbufB[CAP];               // 10400 B (row-sorted)
    __shared__ int  wsum[8];
    __shared__ int  hist[BUCKET_SZ];
    __shared__ int  rp[BUCKET_SZ + 1];
    __shared__ int  cur[BUCKET_SZ];

    const int tid  = threadIdx.x;
    const int b    = blockIdx.x;
    const int wave = tid >> 6;
    const int lane = tid & 63;

    if (tid < BUCKET_SZ) hist[tid] = 0;

    // coalesced segment offsets for this bucket: rows b and b+1 of ofsT
    int s0 = 0, slen = 0;
    if (tid < EBLOCKS) {
        s0   = ofsT[(size_t)b * OFST_W + tid];
        slen = ofsT[(size_t)(b + 1) * OFST_W + tid] - s0;
    }

    // exclusive prefix of slen over 512 threads: per-wave shfl scan + combine
    int iv = slen;
#pragma unroll
    for (int off = 1; off < 64; off <<= 1) {
        int t = __shfl_up(iv, off);
        if (lane >= off) iv += t;
    }
    if (lane == 63) wsum[wave] = iv;
    __syncthreads();
    int wpre = 0, total = 0;
#pragma unroll
    for (int w = 0; w < 8; ++w) {
        int sw = wsum[w];
        total += sw;
        if (w < wave) wpre += sw;
    }
    const int excl = wpre + iv - slen;
    const int n    = min(total, CAP);

    // copy segment into LDS + histogram (fused, one pass)
    {
        const int2* seg = part + (size_t)tid * EBLOCK + s0;
        for (int k = 0; k < slen; ++k) {
            int p = excl + k;
            if (p < CAP) {
                int2 cv = seg[k];
                sbufA[p] = cv;
                atomicAdd(&hist[(cv.x >> 16) & 63], 1);
            }
        }
    }
    __syncthreads();

    // wave 0: 64-bin exclusive scan via one 64-wide shuffle scan
    if (tid < 64) {
        int a = hist[tid];
        int ia = a;
#pragma unroll
        for (int off = 1; off < 64; off <<= 1) {
            int t = __shfl_up(ia, off);
            if (tid >= off) ia += t;
        }
        rp[tid + 1] = ia;
        if (tid == 0) rp[0] = 0;
        cur[tid] = ia - a;
    }
    __syncthreads();

    // place row-sorted
    for (int j = tid; j < n; j += 512) {
        int2 cv = sbufA[j];
        int p = atomicAdd(&cur[(cv.x >> 16) & 63], 1);
        sbufB[p] = cv;
    }
    __syncthreads();

    // accumulate: disjoint rows per wave -> no races; 8-deep ILP
    const int rowLo = wave * 8;
#pragma unroll 1
    for (int r = rowLo; r < rowLo + 8; ++r) {
        const int grow = b * BUCKET_SZ + r;
        if (grow >= N_NODES) break;
        const int s = rp[r], e = rp[r + 1];
        float ax = 0.f, ay = 0.f;
        int j = s;
        for (; j + 7 < e; j += 8) {
            int2 c0 = sbufB[j],     c1 = sbufB[j + 1];
            int2 c2 = sbufB[j + 2], c3 = sbufB[j + 3];
            int2 c4 = sbufB[j + 4], c5 = sbufB[j + 5];
            int2 c6 = sbufB[j + 6], c7 = sbufB[j + 7];
            unsigned u0 = support_u32[(size_t)(c0.x & 0xFFFF) * 64 + lane];
            unsigned u1 = support_u32[(size_t)(c1.x & 0xFFFF) * 64 + lane];
            unsigned u2 = support_u32[(size_t)(c2.x & 0xFFFF) * 64 + lane];
            unsigned u3 = support_u32[(size_t)(c3.x & 0xFFFF) * 64 + lane];
            unsigned u4 = support_u32[(size_t)(c4.x & 0xFFFF) * 64 + lane];
            unsigned u5 = support_u32[(size_t)(c5.x & 0xFFFF) * 64 + lane];
            unsigned u6 = support_u32[(size_t)(c6.x & 0xFFFF) * 64 + lane];
            unsigned u7 = support_u32[(size_t)(c7.x & 0xFFFF) * 64 + lane];
            float v0 = __int_as_float(c0.y), v1 = __int_as_float(c1.y);
            float v2 = __int_as_float(c2.y), v3 = __int_as_float(c3.y);
            float v4 = __int_as_float(c4.y), v5 = __int_as_float(c5.y);
            float v6 = __int_as_float(c6.y), v7 = __int_as_float(c7.y);
            ax += v0 * bfLo(u0); ay += v0 * bfHi(u0);
            ax += v1 * bfLo(u1); ay += v1 * bfHi(u1);
            ax += v2 * bfLo(u2); ay += v2 * bfHi(u2);
            ax += v3 * bfLo(u3); ay += v3 * bfHi(u3);
            ax += v4 * bfLo(u4); ay += v4 * bfHi(u4);
            ax += v5 * bfLo(u5); ay += v5 * bfHi(u5);
            ax += v6 * bfLo(u6); ay += v6 * bfHi(u6);
            ax += v7 * bfLo(u7); ay += v7 * bfHi(u7);
        }
        for (; j + 3 < e; j += 4) {
            int2 c0 = sbufB[j],     c1 = sbufB[j + 1];
            int2 c2 = sbufB[j + 2], c3 = sbufB[j + 3];
            unsigned u0 = support_u32[(size_t)(c0.x & 0xFFFF) * 64 + lane];
            unsigned u1 = support_u32[(size_t)(c1.x & 0xFFFF) * 64 + lane];
            unsigned u2 = support_u32[(size_t)(c2.x & 0xFFFF) * 64 + lane];
            unsigned u3 = support_u32[(size_t)(c3.x & 0xFFFF) * 64 + lane];
            float v0 = __int_as_float(c0.y), v1 = __int_as_float(c1.y);
            float v2 = __int_as_float(c2.y), v3 = __int_as_float(c3.y);
            ax += v0 * bfLo(u0); ay += v0 * bfHi(u0);
            ax += v1 * bfLo(u1); ay += v1 * bfHi(u1);
            ax += v2 * bfLo(u2); ay += v2 * bfHi(u2);
            ax += v3 * bfLo(u3); ay += v3 * bfHi(u3);
        }
        for (; j < e; ++j) {
            int2 cv = sbufB[j];
            unsigned u = support_u32[(size_t)(cv.x & 0xFFFF) * 64 + lane];
            float v = __int_as_float(cv.y);
            ax += v * bfLo(u); ay += v * bfHi(u);
        }
        *(float2*)(out + (size_t)grow * HIDDEN + lane * 2) = make_float2(ax, ay);
    }
}

extern "C" void kernel_launch(void* const* d_in, const int* in_sizes, int n_in,
                              void* d_out, int out_size, void* d_ws, size_t ws_size,
                              hipStream_t stream) {
    const float* x       = (const float*)d_in[0];
    const int*   adj_row = (const int*)d_in[1];
    const int*   adj_col = (const int*)d_in[2];
    const float* adj_val = (const float*)d_in[3];
    const float* W       = (const float*)d_in[4];
    const float* b       = (const float*)d_in[5];
    float* out = (float*)d_out;

    char* wsb = (char*)d_ws;
    const size_t off_support = 0;                                          // 12.8 MB bf16
    const size_t off_part    = off_support + (size_t)N_NODES * HIDDEN * 2;
    const size_t off_ofsT    = off_part + (size_t)EBLOCKS * EBLOCK * 8;    // 6.42 MB
    const size_t off_wb      = off_ofsT + (size_t)(NB + 1) * OFST_W * 4;   // 0.80 MB
    // wb: 64 KB; total ~20.1 MB

    unsigned short* support = (unsigned short*)(wsb + off_support);
    int2* part = (int2*)(wsb + off_part);
    int*  ofsT = (int*)(wsb + off_ofsT);
    unsigned short* wb = (unsigned short*)(wsb + off_wb);

    wconv_kernel<<<NFRAG / 256, 256, 0, stream>>>(W, wb);
    fused_linear_partition_kernel<<<NTASKS, 256, 0, stream>>>(
        x, wb, b, support, adj_row, adj_col, adj_val, part, ofsT);
    bucket_gather_kernel<<<NB, 512, 0, stream>>>(
        ofsT, part, (const unsigned int*)support, out);
}

// Round 7
// 155.866 us; speedup vs baseline: 2.0461x; 1.0016x over previous
//
#include <hip/hip_runtime.h>

#define N_NODES 50000
#define N_EDGES 800000
#define IN_F    256
#define HIDDEN  128

#define BUCKET_SZ 64                      // rows per bucket
#define NB        782                     // ceil(N_NODES / 64)
#define NBINS     1024                    // padded scan width (4 per thread x 256)
#define EBLOCK    3328                    // edges per partition task (13 x 256)
#define EPT       13                      // edges per thread
#define EBLOCKS   241                     // ceil(800000 / 3328)
#define LIN_ROWS  64                      // rows per linear task
#define LBLOCKS   782                     // ceil(50000 / 64)
#define NTASKS    1023                    // EBLOCKS + LBLOCKS (= 4.0 blocks/CU)
#define OFST_W    256                     // ofsT row width (241 used, padded)
#define CAP       1300                    // max entries per bucket in LDS (mean 1024, +8.6 sigma)
#define NFRAG     4096                    // W bf16 fragments: 8 hk x 8 s x 64 lanes

// fused-kernel LDS: partition branch only (linear branch uses none).
#define SMEM_BYTES 35840

typedef __attribute__((ext_vector_type(8))) short bf16x8;
typedef __attribute__((ext_vector_type(4))) float f32x4;

__device__ inline unsigned short f2bf(float f) {
    unsigned u = __float_as_uint(f);
    u += 0x7FFF + ((u >> 16) & 1);          // round-to-nearest-even
    return (unsigned short)(u >> 16);
}
__device__ inline bf16x8 cvt8(float4 a, float4 b) {
    bf16x8 r;
    r[0] = (short)f2bf(a.x); r[1] = (short)f2bf(a.y);
    r[2] = (short)f2bf(a.z); r[3] = (short)f2bf(a.w);
    r[4] = (short)f2bf(b.x); r[5] = (short)f2bf(b.y);
    r[6] = (short)f2bf(b.z); r[7] = (short)f2bf(b.w);
    return r;
}
__device__ inline float bfLo(unsigned u) { return __uint_as_float(u << 16); }
__device__ inline float bfHi(unsigned u) { return __uint_as_float(u & 0xFFFF0000u); }

// ---------------------------------------------------------------------------
// W pre-convert: f32 W[128][256] -> bf16 MFMA B-fragments (64 KB), fragment
// order wb[((hk*8 + s)*64 + lane)*8 ..]; runs once, L2-hot thereafter.
// ---------------------------------------------------------------------------
__global__ __launch_bounds__(256) void wconv_kernel(
    const float* __restrict__ W, unsigned short* __restrict__ wb)
{
    const int f = blockIdx.x * 256 + threadIdx.x;     // 0..4095
    if (f >= NFRAG) return;
    const int ln = f & 63;
    const int s  = (f >> 6) & 7;
    const int hk = f >> 9;
    const int row = s * 16 + (ln & 15);
    const int k0  = hk * 32 + (ln >> 4) * 8;
    const float* wp = W + (size_t)row * IN_F + k0;
    float4 b0 = *(const float4*)wp;
    float4 b1 = *(const float4*)(wp + 4);
    *(bf16x8*)(wb + (size_t)f * 8) = cvt8(b0, b1);
}

// ---------------------------------------------------------------------------
// Fused kernel (unchanged from round 6). Blocks [0, EBLOCKS): edge partition
// (deterministic per-task layout + transposed offsets). Blocks [EBLOCKS,
// NTASKS): LDS-free MFMA linear, 64 rows each.
// ---------------------------------------------------------------------------
__global__ __launch_bounds__(256, 4) void fused_linear_partition_kernel(
    const float* __restrict__ x, const unsigned short* __restrict__ wb,
    const float* __restrict__ bias, unsigned short* __restrict__ support,
    const int* __restrict__ adj_row, const int* __restrict__ adj_col,
    const float* __restrict__ adj_val,
    int2* __restrict__ part, int* __restrict__ ofsT)
{
    const int tid = threadIdx.x;

    if (blockIdx.x < EBLOCKS) {
        // ================= PARTITION branch =================
        __shared__ __align__(16) char smem[SMEM_BYTES];
        int2* lbuf = (int2*)smem;                    // 26624 B (3328 entries)
        int*  lofs = (int*)(smem + 26624);           // 4096 B (counts -> excl offsets)
        int*  lcur = (int*)(smem + 30720);           // 4096 B
        int*  tsum = (int*)(smem + 34816);           // 1024 B

        const int task = blockIdx.x;
        const int base = task * EBLOCK;
        const int n    = min(EBLOCK, N_EDGES - base);

        for (int i = tid; i < NBINS; i += 256) lofs[i] = 0;
        __syncthreads();

        unsigned pk[EPT]; float pv[EPT];
#pragma unroll
        for (int i = 0; i < EPT; ++i) {
            int li = tid + i * 256;
            bool ok = li < n;
            int ee = ok ? (base + li) : base;
            int r = adj_row[ee], c = adj_col[ee];
            float v = adj_val[ee];
            if (ok) {
                unsigned bk = (unsigned)r >> 6;
                pk[i] = (bk << 22) | (((unsigned)r & 63u) << 16) | (unsigned)c;
                pv[i] = v;
                atomicAdd(&lofs[bk], 1);
            } else pk[i] = 0xFFFFFFFFu;
        }
        __syncthreads();

        // exclusive scan over 1024 bins: 4 per thread + Hillis-Steele over 256
        int s0 = lofs[tid * 4], s1 = lofs[tid * 4 + 1];
        int s2 = lofs[tid * 4 + 2], s3 = lofs[tid * 4 + 3];
        int mysum = s0 + s1 + s2 + s3;
        tsum[tid] = mysum;
        __syncthreads();
#pragma unroll
        for (int off = 1; off < 256; off <<= 1) {
            int t = (tid >= off) ? tsum[tid - off] : 0;
            __syncthreads();
            tsum[tid] += t;
            __syncthreads();
        }
        int ex = tsum[tid] - mysum;
        lofs[tid * 4]     = ex;
        lofs[tid * 4 + 1] = ex + s0;
        lofs[tid * 4 + 2] = ex + s0 + s1;
        lofs[tid * 4 + 3] = ex + s0 + s1 + s2;
        __syncthreads();

        // init scatter cursors
        for (int i = tid; i < NBINS; i += 256) lcur[i] = lofs[i];
        __syncthreads();

        // group into lbuf (bucket-contiguous)
#pragma unroll
        for (int i = 0; i < EPT; ++i) {
            if (pk[i] != 0xFFFFFFFFu) {
                unsigned bk = pk[i] >> 22;
                int p = atomicAdd(&lcur[bk], 1);
                lbuf[p] = make_int2((int)(pk[i] & 0x3FFFFF), __float_as_int(pv[i]));
            }
        }
        __syncthreads();

        // write run data (coalesced) + transposed offsets column
        for (int j = tid; j < n; j += 256)
            part[(size_t)task * EBLOCK + j] = lbuf[j];
        for (int i = tid; i <= NB; i += 256)
            ofsT[(size_t)i * OFST_W + task] = lofs[i];
    } else {
        // ================= LINEAR branch (64 rows, LDS-free) =================
        const int bid  = blockIdx.x - EBLOCKS;
        const int lane = tid & 63;
        const int wave = tid >> 6;
        const int quad = lane >> 4;
        const int l16  = lane & 15;

        int m = bid * LIN_ROWS + wave * 16 + l16;
        if (m >= N_NODES) m = N_NODES - 1;
        const float* xrow = x + (size_t)m * IN_F;
        const bf16x8* wbv = (const bf16x8*)wb;

        f32x4 acc[8];
#pragma unroll
        for (int s = 0; s < 8; ++s) acc[s] = (f32x4){0.f, 0.f, 0.f, 0.f};

#pragma unroll 2
        for (int hk = 0; hk < 8; ++hk) {
            const int k0 = hk * 32 + quad * 8;
            float4 a0 = *(const float4*)(xrow + k0);
            float4 a1 = *(const float4*)(xrow + k0 + 4);
            bf16x8 af = cvt8(a0, a1);
            const bf16x8* bb = wbv + (size_t)hk * 512 + lane;
#pragma unroll
            for (int s = 0; s < 8; ++s) {
                bf16x8 bf = bb[(size_t)s * 64];
                acc[s] = __builtin_amdgcn_mfma_f32_16x16x32_bf16(af, bf, acc[s], 0, 0, 0);
            }
        }

        const int rowBase = bid * LIN_ROWS + wave * 16 + quad * 4;
#pragma unroll
        for (int reg = 0; reg < 4; ++reg) {
            const int r = rowBase + reg;
            if (r < N_NODES) {
#pragma unroll
                for (int s = 0; s < 8; ++s) {
                    const int col = s * 16 + l16;
                    float v = acc[s][reg] + bias[col];
                    support[(size_t)r * HIDDEN + col] = f2bf(v);
                }
            }
        }
    }
}

// ---------------------------------------------------------------------------
// Bucket gather: 512 threads per 64-row bucket. Copy+histogram / scan /
// row-sort as before. NEW accumulate: quarter-wave per edge — 16 lanes x
// dwordx4 (16 B) cover one 256 B support row, 4 edges per wave-step,
// unrolled x2 (8 edges, 2 independent load chains/lane). 4x fewer VMEM
// issues per edge. Cross-quad reduce: shfl_xor 16 & 32; store mapping:
// lane (q,l16) writes cols l16*8+2q, +2q+1 (its own regs, static select).
// ---------------------------------------------------------------------------
__global__ __launch_bounds__(512) void bucket_gather_kernel(
    const int* __restrict__ ofsT, const int2* __restrict__ part,
    const unsigned int* __restrict__ support_u32, float* __restrict__ out)
{
    __shared__ int2 sbufA[CAP];               // 10400 B (unsorted)
    __shared__ int2 sbufB[CAP];               // 10400 B (row-sorted)
    __shared__ int  wsum[8];
    __shared__ int  hist[BUCKET_SZ];
    __shared__ int  rp[BUCKET_SZ + 1];
    __shared__ int  cur[BUCKET_SZ];

    const int tid  = threadIdx.x;
    const int b    = blockIdx.x;
    const int wave = tid >> 6;
    const int lane = tid & 63;

    if (tid < BUCKET_SZ) hist[tid] = 0;

    // coalesced segment offsets for this bucket: rows b and b+1 of ofsT
    int s0 = 0, slen = 0;
    if (tid < EBLOCKS) {
        s0   = ofsT[(size_t)b * OFST_W + tid];
        slen = ofsT[(size_t)(b + 1) * OFST_W + tid] - s0;
    }

    // exclusive prefix of slen over 512 threads: per-wave shfl scan + combine
    int iv = slen;
#pragma unroll
    for (int off = 1; off < 64; off <<= 1) {
        int t = __shfl_up(iv, off);
        if (lane >= off) iv += t;
    }
    if (lane == 63) wsum[wave] = iv;
    __syncthreads();
    int wpre = 0, total = 0;
#pragma unroll
    for (int w = 0; w < 8; ++w) {
        int sw = wsum[w];
        total += sw;
        if (w < wave) wpre += sw;
    }
    const int excl = wpre + iv - slen;
    const int n    = min(total, CAP);

    // copy segment into LDS + histogram (fused, one pass)
    {
        const int2* seg = part + (size_t)tid * EBLOCK + s0;
        for (int k = 0; k < slen; ++k) {
            int p = excl + k;
            if (p < CAP) {
                int2 cv = seg[k];
                sbufA[p] = cv;
                atomicAdd(&hist[(cv.x >> 16) & 63], 1);
            }
        }
    }
    __syncthreads();

    // wave 0: 64-bin exclusive scan via one 64-wide shuffle scan
    if (tid < 64) {
        int a = hist[tid];
        int ia = a;
#pragma unroll
        for (int off = 1; off < 64; off <<= 1) {
            int t = __shfl_up(ia, off);
            if (tid >= off) ia += t;
        }
        rp[tid + 1] = ia;
        if (tid == 0) rp[0] = 0;
        cur[tid] = ia - a;
    }
    __syncthreads();

    // place row-sorted
    for (int j = tid; j < n; j += 512) {
        int2 cv = sbufA[j];
        int p = atomicAdd(&cur[(cv.x >> 16) & 63], 1);
        sbufB[p] = cv;
    }
    __syncthreads();

    // accumulate: wave owns rows [8w, 8w+8); quarter-wave per edge
    const int q   = lane >> 4;                // 0..3
    const int l16 = lane & 15;
    const uint4* support4 = (const uint4*)support_u32;   // 16 B blocks
    const int rowLo = wave * 8;
#pragma unroll 1
    for (int r = rowLo; r < rowLo + 8; ++r) {
        const int grow = b * BUCKET_SZ + r;
        if (grow >= N_NODES) break;
        const int s = rp[r], e = rp[r + 1];
        float a0 = 0.f, a1 = 0.f, a2 = 0.f, a3 = 0.f;
        float a4 = 0.f, a5 = 0.f, a6 = 0.f, a7 = 0.f;
        for (int j = s; j < e; j += 8) {
            // chain A: edge j + q
            int iA  = j + q;
            int icA = min(iA, e - 1);
            int2 cA = sbufB[icA];
            float vA = (iA < e) ? __int_as_float(cA.y) : 0.f;
            uint4 uA = support4[(size_t)(cA.x & 0xFFFF) * 16 + l16];
            // chain B: edge j + 4 + q
            int iB  = j + 4 + q;
            int icB = min(iB, e - 1);
            int2 cB = sbufB[icB];
            float vB = (iB < e) ? __int_as_float(cB.y) : 0.f;
            uint4 uB = support4[(size_t)(cB.x & 0xFFFF) * 16 + l16];

            a0 += vA * bfLo(uA.x); a1 += vA * bfHi(uA.x);
            a2 += vA * bfLo(uA.y); a3 += vA * bfHi(uA.y);
            a4 += vA * bfLo(uA.z); a5 += vA * bfHi(uA.z);
            a6 += vA * bfLo(uA.w); a7 += vA * bfHi(uA.w);
            a0 += vB * bfLo(uB.x); a1 += vB * bfHi(uB.x);
            a2 += vB * bfLo(uB.y); a3 += vB * bfHi(uB.y);
            a4 += vB * bfLo(uB.z); a5 += vB * bfHi(uB.z);
            a6 += vB * bfLo(uB.w); a7 += vB * bfHi(uB.w);
        }
        // reduce across quarter-waves (lane^16, lane^32)
        a0 += __shfl_xor(a0, 16); a0 += __shfl_xor(a0, 32);
        a1 += __shfl_xor(a1, 16); a1 += __shfl_xor(a1, 32);
        a2 += __shfl_xor(a2, 16); a2 += __shfl_xor(a2, 32);
        a3 += __shfl_xor(a3, 16); a3 += __shfl_xor(a3, 32);
        a4 += __shfl_xor(a4, 16); a4 += __shfl_xor(a4, 32);
        a5 += __shfl_xor(a5, 16); a5 += __shfl_xor(a5, 32);
        a6 += __shfl_xor(a6, 16); a6 += __shfl_xor(a6, 32);
        a7 += __shfl_xor(a7, 16); a7 += __shfl_xor(a7, 32);
        // store: lane (q,l16) writes cols l16*8 + 2q, 2q+1 (static select)
        float s0v, s1v;
        if      (q == 0) { s0v = a0; s1v = a1; }
        else if (q == 1) { s0v = a2; s1v = a3; }
        else if (q == 2) { s0v = a4; s1v = a5; }
        else             { s0v = a6; s1v = a7; }
        *(float2*)(out + (size_t)grow * HIDDEN + l16 * 8 + q * 2) = make_float2(s0v, s1v);
    }
}

extern "C" void kernel_launch(void* const* d_in, const int* in_sizes, int n_in,
                              void* d_out, int out_size, void* d_ws, size_t ws_size,
                              hipStream_t stream) {
    const float* x       = (const float*)d_in[0];
    const int*   adj_row = (const int*)d_in[1];
    const int*   adj_col = (const int*)d_in[2];
    const float* adj_val = (const float*)d_in[3];
    const float* W       = (const float*)d_in[4];
    const float* b       = (const float*)d_in[5];
    float* out = (float*)d_out;

    char* wsb = (char*)d_ws;
    const size_t off_support = 0;                                          // 12.8 MB bf16
    const size_t off_part    = off_support + (size_t)N_NODES * HIDDEN * 2;
    const size_t off_ofsT    = off_part + (size_t)EBLOCKS * EBLOCK * 8;    // 6.42 MB
    const size_t off_wb      = off_ofsT + (size_t)(NB + 1) * OFST_W * 4;   // 0.80 MB
    // wb: 64 KB; total ~20.1 MB

    unsigned short* support = (unsigned short*)(wsb + off_support);
    int2* part = (int2*)(wsb + off_part);
    int*  ofsT = (int*)(wsb + off_ofsT);
    unsigned short* wb = (unsigned short*)(wsb + off_wb);

    wconv_kernel<<<NFRAG / 256, 256, 0, stream>>>(W, wb);
    fused_linear_partition_kernel<<<NTASKS, 256, 0, stream>>>(
        x, wb, b, support, adj_row, adj_col, adj_val, part, ofsT);
    bucket_gather_kernel<<<NB, 512, 0, stream>>>(
        ofsT, part, (const unsigned int*)support, out);
}